// Round 9
// baseline (1499.375 us; speedup 1.0000x reference)
//
#include <hip/hip_runtime.h>
#include <hip/hip_bf16.h>

typedef __hip_bfloat16 bf16;

__device__ __forceinline__ float b2f(bf16 v) { return __bfloat162float(v); }
__device__ __forceinline__ float lo16(unsigned int u) {
    union { unsigned int i; float f; } x; x.i = u << 16; return x.f;
}
__device__ __forceinline__ float hi16(unsigned int u) {
    union { unsigned int i; float f; } x; x.i = u & 0xffff0000u; return x.f;
}

// load 8 consecutive channel values as f32 (bf16 or f32 source)
template<typename T>
__device__ __forceinline__ void load8(const T* p, float o[8]);
template<>
__device__ __forceinline__ void load8<bf16>(const bf16* p, float o[8]) {
    uint4 v = *reinterpret_cast<const uint4*>(p);
    o[0] = lo16(v.x); o[1] = hi16(v.x);
    o[2] = lo16(v.y); o[3] = hi16(v.y);
    o[4] = lo16(v.z); o[5] = hi16(v.z);
    o[6] = lo16(v.w); o[7] = hi16(v.w);
}
template<>
__device__ __forceinline__ void load8<float>(const float* p, float o[8]) {
    float4 a = reinterpret_cast<const float4*>(p)[0];
    float4 b = reinterpret_cast<const float4*>(p)[1];
    o[0] = a.x; o[1] = a.y; o[2] = a.z; o[3] = a.w;
    o[4] = b.x; o[5] = b.y; o[6] = b.z; o[7] = b.w;
}
__device__ __forceinline__ void store1(bf16* p, float v)  { *p = __float2bfloat16(v); }
__device__ __forceinline__ void store1(float* p, float v) { *p = v; }

// ---------------------------------------------------------------------------
// diagnostics (kept; ~15us total)
// ---------------------------------------------------------------------------
__global__ void k_chk16(const unsigned short* __restrict__ buf, size_t n,
                        int stage, int* __restrict__ flag)
{
    size_t i0 = (size_t)blockIdx.x * blockDim.x + threadIdx.x;
    size_t stride = (size_t)gridDim.x * blockDim.x;
    int found = 0;
    for (size_t i = i0; i < n; i += stride) {
        unsigned short u = buf[i];
        if ((u & 0x7fffu) >= 0x7f80u) { found = 1; break; }
    }
    if (found) atomicCAS(flag, 0, stage);
}
__global__ void k_chk32(const unsigned int* __restrict__ buf, size_t n,
                        int stage, int* __restrict__ flag)
{
    size_t i0 = (size_t)blockIdx.x * blockDim.x + threadIdx.x;
    size_t stride = (size_t)gridDim.x * blockDim.x;
    int found = 0;
    for (size_t i = i0; i < n; i += stride) {
        unsigned int u = buf[i];
        if (((u >> 23) & 0xffu) == 0xffu) { found = 1; break; }
    }
    if (found) atomicCAS(flag, 0, stage);
}
__global__ void k_code(float* __restrict__ out, size_t n, float code)
{
    size_t i0 = (size_t)blockIdx.x * blockDim.x + threadIdx.x;
    size_t stride = (size_t)gridDim.x * blockDim.x;
    for (size_t i = i0; i < n; i += stride) out[i] = code;
}
__global__ void k_pub(float* __restrict__ y, size_t n, const int* __restrict__ flag)
{
    int f = *flag;
    if (f == 0) return;
    size_t i0 = (size_t)blockIdx.x * blockDim.x + threadIdx.x;
    size_t stride = (size_t)gridDim.x * blockDim.x;
    float v = 100.f + (float)f;
    for (size_t i = i0; i < n; i += stride) y[i] = v;
}

// ---------------------------------------------------------------------------
// Stage A: h = prelu(concat(rec_F, bins1_F) @ W_dec + b_dec, a_dec)   [N,64]
// ALL float inputs f32 (reference dtype). h stored bf16 in ws.
// ---------------------------------------------------------------------------
__global__ __launch_bounds__(256) void k_dec(
    const float* __restrict__ rec, const float* __restrict__ bins,
    const float* __restrict__ W, const float* __restrict__ b, const float* __restrict__ a,
    bf16* __restrict__ h, int N)
{
    __shared__ float Wl[72 * 64];
    int tid = threadIdx.x;
    for (int i = tid; i < 72 * 64; i += 256) Wl[i] = W[i];
    int c = tid & 63, w = tid >> 6;
    float bc = b[c];
    float av = a[0];
    __syncthreads();
    int base = blockIdx.x * 32 + w * 8;
    for (int rr = 0; rr < 8; ++rr) {
        int row = base + rr;
        if (row >= N) break;
        float acc = bc;
        float xv[8];
        #pragma unroll
        for (int j8 = 0; j8 < 8; ++j8) {
            load8(rec + (size_t)row * 64 + j8 * 8, xv);
            int j = j8 * 8;
            #pragma unroll
            for (int t = 0; t < 8; ++t) acc += xv[t] * Wl[(j + t) * 64 + c];
        }
        load8(bins + (size_t)row * 8, xv);
        #pragma unroll
        for (int t = 0; t < 8; ++t) acc += xv[t] * Wl[(64 + t) * 64 + c];
        float v = acc >= 0.f ? acc : av * acc;
        h[(size_t)row * 64 + c] = __float2bfloat16(v);
    }
}

// ---------------------------------------------------------------------------
// Sparse 3x3x3 conv with validity skip:
//   out[i][c] = prelu(b + sum_k x[nbr[i,k]] @ W[k][:,c] (+res), a)
// Lanes of a wave share the same 8 rows => idxs lane-uniform => wave validity
// free. Block vote via parity-double-buffered sflag published at barrier A
// (which also protects Wl reuse). Skipped k: 1 barrier, no staging, no wreg.
// ---------------------------------------------------------------------------
template<typename TIN, typename TOUT, bool RES>
__global__ __launch_bounds__(256) void k_sconv(
    const TIN* __restrict__ x, const int* __restrict__ nbr,
    const float* __restrict__ W, const float* __restrict__ bias, const float* __restrict__ a,
    const bf16* __restrict__ res, TOUT* __restrict__ out, int N)
{
    __shared__ float Wl[64 * 64];
    __shared__ int sflag[2][4];
    int tid = threadIdx.x;
    int c = tid & 63, w = tid >> 6;
    float bc = bias[c];
    float av = a[0];
    float acc[8];
    #pragma unroll
    for (int rr = 0; rr < 8; ++rr) acc[rr] = bc;
    int base = blockIdx.x * 32 + w * 8;

    for (int k = 0; k < 27; ++k) {
        int idxs[8];
        int any = 0;
        #pragma unroll
        for (int rr = 0; rr < 8; ++rr) {
            int row = base + rr;
            idxs[rr] = (row < N) ? nbr[(size_t)row * 27 + k] : -1;
            any |= (idxs[rr] >= 0) ? 1 : 0;   // lane-uniform within the wave
        }
        if (c == 0) sflag[k & 1][w] = any;
        // barrier A: prev-iter Wl reads done; sflag[k&1] visible. Writes to
        // sflag[k&1] for iter k+2 are ordered after barrier A of k+1 -> no race.
        __syncthreads();
        int block_any = sflag[k & 1][0] | sflag[k & 1][1] | sflag[k & 1][2] | sflag[k & 1][3];
        if (!block_any) continue;   // block-uniform -> barrier sequences stay aligned

        // stage W[k]: 4096 f32, 16 per thread
        {
            const float4* src = reinterpret_cast<const float4*>(W + (size_t)k * 4096);
            #pragma unroll
            for (int t = 0; t < 4; ++t) {
                int i = t * 256 + tid;
                reinterpret_cast<float4*>(Wl)[i] = src[i];
            }
        }
        __syncthreads();   // barrier B: Wl ready

        if (any) {          // wave-uniform: skip wreg reads when wave idle
            #pragma unroll
            for (int jt = 0; jt < 8; ++jt) {
                float wreg[8];
                #pragma unroll
                for (int t = 0; t < 8; ++t) wreg[t] = Wl[(jt * 8 + t) * 64 + c];
                #pragma unroll
                for (int rr = 0; rr < 8; ++rr) {
                    int idx = idxs[rr];
                    if (idx < 0) continue;   // wave-uniform
                    float xv[8];
                    load8(x + (size_t)idx * 64 + jt * 8, xv);
                    #pragma unroll
                    for (int t = 0; t < 8; ++t) acc[rr] += xv[t] * wreg[t];
                }
            }
        }
    }
    #pragma unroll
    for (int rr = 0; rr < 8; ++rr) {
        int row = base + rr;
        if (row >= N) break;
        float v = acc[rr];
        if (RES) v += b2f(res[(size_t)row * 64 + c]);
        v = v >= 0.f ? v : av * v;
        store1(out + (size_t)row * 64 + c, v);
    }
}

// ---------------------------------------------------------------------------
// pred[0] linear + bool-mask gather, fused (W: f32 [64,512], L2-resident)
// ---------------------------------------------------------------------------
__global__ __launch_bounds__(256) void k_p0l(
    const bf16* __restrict__ p, const float* __restrict__ W, const float* __restrict__ b,
    const int* __restrict__ pidx, const int* __restrict__ bitj,
    bf16* __restrict__ g, int M)
{
    int tid = threadIdx.x;
    int c = tid & 63, w = tid >> 6;
    int base = blockIdx.x * 32 + w * 8;
    for (int rr = 0; rr < 8; ++rr) {
        int m = base + rr;
        if (m >= M) break;
        int pi = pidx[m];
        int bt = bitj[m];
        int col = bt * 64 + c;
        float acc = b[col];
        float xv[8];
        #pragma unroll
        for (int j8 = 0; j8 < 8; ++j8) {
            load8(p + (size_t)pi * 64 + j8 * 8, xv);
            int j = j8 * 8;
            #pragma unroll
            for (int t = 0; t < 8; ++t)
                acc += xv[t] * W[(size_t)(j + t) * 512 + col];
        }
        g[(size_t)m * 64 + c] = __float2bfloat16(acc);
    }
}

// ---------------------------------------------------------------------------
// loss: logits = q @ Wp1l + b -> log_softmax -> ce/pn -> atomic accum
// ---------------------------------------------------------------------------
__global__ __launch_bounds__(256) void k_loss(
    const bf16* __restrict__ q, const float* __restrict__ W, const float* __restrict__ b,
    const int* __restrict__ bins0, const int* __restrict__ octk,
    const int* __restrict__ ref_batch, const float* __restrict__ pn,
    float* __restrict__ accum, int M)
{
    __shared__ float Wl[64 * 256];
    int tid = threadIdx.x;
    for (int i = tid; i < 64 * 255; i += 256) {
        int j = i / 255, col = i - j * 255;
        Wl[j * 256 + col] = W[i];
    }
    if (tid < 64) Wl[tid * 256 + 255] = 0.f;
    int lane = tid & 63, w = tid >> 6;
    float bcol[4];
    #pragma unroll
    for (int t = 0; t < 4; ++t) {
        int col = lane + 64 * t;
        bcol[t] = (col < 255) ? b[col] : 0.f;
    }
    int ok[8];
    #pragma unroll
    for (int j = 0; j < 8; ++j) ok[j] = octk[j];
    __syncthreads();

    float local = 0.f;
    int waveId = blockIdx.x * 4 + w;
    int nWaves = gridDim.x * 4;
    for (int m = waveId; m < M; m += nWaves) {
        float acc[4] = { bcol[0], bcol[1], bcol[2], bcol[3] };
        float xj[8];
        #pragma unroll
        for (int j8 = 0; j8 < 8; ++j8) {
            load8(q + (size_t)m * 64 + j8 * 8, xj);
            #pragma unroll
            for (int jj = 0; jj < 8; ++jj) {
                int j = j8 * 8 + jj;
                #pragma unroll
                for (int t = 0; t < 4; ++t)
                    acc[t] += xj[jj] * Wl[j * 256 + lane + 64 * t];
            }
        }
        float mx = -1e30f;
        #pragma unroll
        for (int t = 0; t < 4; ++t) {
            int col = lane + 64 * t;
            float v = (col < 255) ? acc[t] : -1e30f;
            mx = fmaxf(mx, v);
        }
        #pragma unroll
        for (int s = 32; s > 0; s >>= 1) mx = fmaxf(mx, __shfl_xor(mx, s, 64));
        float se = 0.f;
        #pragma unroll
        for (int t = 0; t < 4; ++t) {
            int col = lane + 64 * t;
            if (col < 255) se += __expf(acc[t] - mx);
        }
        #pragma unroll
        for (int s = 32; s > 0; s >>= 1) se += __shfl_xor(se, s, 64);
        int oct = 0;
        #pragma unroll
        for (int j = 0; j < 8; ++j) oct += bins0[(size_t)m * 8 + j] << ok[j];
        oct -= 1;
        int tl = oct >> 6, ln = oct & 63;
        float lo = (tl == 0) ? acc[0] : (tl == 1) ? acc[1] : (tl == 2) ? acc[2] : acc[3];
        lo = __shfl(lo, ln, 64);
        float ce = mx + __logf(se) - lo;
        float pnv = pn[ref_batch[m]];
        local += ce / pnv;
    }
    if (lane == 0) atomicAdd(accum, local);
}

__global__ void k_finish(const float* __restrict__ accum, float* __restrict__ outf,
                         int BATCH, int* __restrict__ flag)
{
    if (threadIdx.x == 0 && blockIdx.x == 0) {
        float loss = accum[0] * 1.4426950408889634f / (float)BATCH;
        if (!(loss == loss) || fabsf(loss) > 1e30f) atomicCAS(flag, 0, 7);
        outf[0] = loss;
    }
}

// ---------------------------------------------------------------------------
// Inputs f32 (reference dtype); d_out f32; internal ws bufs bf16.
// ws: [0,4) accum | [4,8) flag | pad 64 | buf1, buf2 (M*64 bf16 each = 41.2MB)
// Diagnostics: ws too small -> y=200+MB; NaN at stage s -> y=100+s.
// ---------------------------------------------------------------------------
extern "C" void kernel_launch(void* const* d_in, const int* in_sizes, int n_in,
                              void* d_out, int out_size, void* d_ws, size_t ws_size,
                              hipStream_t stream)
{
    const float* rec_F   = (const float*)d_in[0];
    const float* bins1_F = (const float*)d_in[1];
    const float* pn      = (const float*)d_in[2];
    const float* W_dec   = (const float*)d_in[3];
    const float* b_dec   = (const float*)d_in[4];
    const float* a_dec   = (const float*)d_in[5];
    const float* Wb1     = (const float*)d_in[6];
    const float* bb1     = (const float*)d_in[7];
    const float* ab1     = (const float*)d_in[8];
    const float* Wb2     = (const float*)d_in[9];
    const float* bb2     = (const float*)d_in[10];
    const float* ab2     = (const float*)d_in[11];
    const float* Wp0c    = (const float*)d_in[12];
    const float* bp0c    = (const float*)d_in[13];
    const float* ap0     = (const float*)d_in[14];
    const float* Wp0l    = (const float*)d_in[15];
    const float* bp0l    = (const float*)d_in[16];
    const float* Wp1c    = (const float*)d_in[17];
    const float* bp1c    = (const float*)d_in[18];
    const float* ap1     = (const float*)d_in[19];
    const float* Wp1l    = (const float*)d_in[20];
    const float* bp1l    = (const float*)d_in[21];
    const int* nbr_rec    = (const int*)d_in[22];
    const int* nbr_child  = (const int*)d_in[23];
    const int* child_pidx = (const int*)d_in[24];
    const int* child_bit  = (const int*)d_in[25];
    const int* bins0      = (const int*)d_in[26];
    const int* oct_kernel = (const int*)d_in[27];
    const int* ref_batch  = (const int*)d_in[28];

    int N = in_sizes[0] / 64;
    int M = in_sizes[24];
    int BATCH = in_sizes[2];

    size_t N64 = (size_t)N * 64, M64 = (size_t)M * 64;
    float* out_y    = (float*)d_out;
    float* out_loss = out_y + N64;

    size_t required = 64 + 4 * M64;
    if (ws_size < required) {
        float code = 200.f + (float)(ws_size >> 20);
        k_code<<<512, 256, 0, stream>>>(out_y, N64, code);
        k_code<<<1, 64, 0, stream>>>(out_loss, 1, code);
        return;
    }

    char* wsb = (char*)d_ws;
    float* accum = (float*)wsb;
    int*   flag  = (int*)(wsb + 4);
    bf16* buf1 = (bf16*)(wsb + 64);
    bf16* buf2 = buf1 + M64;

    hipMemsetAsync(wsb, 0, 64, stream);

    int blocksN = (N + 31) / 32;
    int blocksM = (M + 31) / 32;

    k_dec<<<blocksN, 256, 0, stream>>>(rec_F, bins1_F, W_dec, b_dec, a_dec, buf1, N);
    k_chk16<<<256, 256, 0, stream>>>((const unsigned short*)buf1, N64, 1, flag);

    k_sconv<bf16, bf16, false><<<blocksN, 256, 0, stream>>>(buf1, nbr_rec, Wb1, bb1, ab1, nullptr, buf2, N);
    k_chk16<<<256, 256, 0, stream>>>((const unsigned short*)buf2, N64, 2, flag);

    // stage 3 writes y directly to d_out as f32 (residual = buf1)
    k_sconv<bf16, float, true><<<blocksN, 256, 0, stream>>>(buf2, nbr_rec, Wb2, bb2, ab2, buf1, out_y, N);
    k_chk32<<<256, 256, 0, stream>>>((const unsigned int*)out_y, N64, 3, flag);

    k_sconv<float, bf16, false><<<blocksN, 256, 0, stream>>>(out_y, nbr_rec, Wp0c, bp0c, ap0, nullptr, buf1, N);
    k_chk16<<<256, 256, 0, stream>>>((const unsigned short*)buf1, N64, 4, flag);

    k_p0l<<<blocksM, 256, 0, stream>>>(buf1, Wp0l, bp0l, child_pidx, child_bit, buf2, M);
    k_chk16<<<256, 256, 0, stream>>>((const unsigned short*)buf2, M64, 5, flag);

    k_sconv<bf16, bf16, false><<<blocksM, 256, 0, stream>>>(buf2, nbr_child, Wp1c, bp1c, ap1, nullptr, buf1, M);
    k_chk16<<<256, 256, 0, stream>>>((const unsigned short*)buf1, M64, 6, flag);

    k_loss<<<512, 256, 0, stream>>>(buf1, Wp1l, bp1l, bins0, oct_kernel, ref_batch, pn, accum, M);
    k_finish<<<1, 64, 0, stream>>>(accum, out_loss, BATCH, flag);

    k_pub<<<512, 256, 0, stream>>>(out_y, N64, flag);
}

// Round 10
// 875.610 us; speedup vs baseline: 1.7124x; 1.7124x over previous
//
#include <hip/hip_runtime.h>
#include <hip/hip_bf16.h>

typedef __hip_bfloat16 bf16;
typedef __attribute__((ext_vector_type(8))) short bf16x8v;
typedef __attribute__((ext_vector_type(4))) float f32x4v;

__device__ __forceinline__ float b2f(bf16 v) { return __bfloat162float(v); }
__device__ __forceinline__ float lo16(unsigned int u) {
    union { unsigned int i; float f; } x; x.i = u << 16; return x.f;
}
__device__ __forceinline__ float hi16(unsigned int u) {
    union { unsigned int i; float f; } x; x.i = u & 0xffff0000u; return x.f;
}
template<typename T>
__device__ __forceinline__ void load8(const T* p, float o[8]);
template<>
__device__ __forceinline__ void load8<bf16>(const bf16* p, float o[8]) {
    uint4 v = *reinterpret_cast<const uint4*>(p);
    o[0] = lo16(v.x); o[1] = hi16(v.x);
    o[2] = lo16(v.y); o[3] = hi16(v.y);
    o[4] = lo16(v.z); o[5] = hi16(v.z);
    o[6] = lo16(v.w); o[7] = hi16(v.w);
}
template<>
__device__ __forceinline__ void load8<float>(const float* p, float o[8]) {
    float4 a = reinterpret_cast<const float4*>(p)[0];
    float4 b = reinterpret_cast<const float4*>(p)[1];
    o[0] = a.x; o[1] = a.y; o[2] = a.z; o[3] = a.w;
    o[4] = b.x; o[5] = b.y; o[6] = b.z; o[7] = b.w;
}

__global__ void k_code(float* __restrict__ out, size_t n, float code)
{
    size_t i0 = (size_t)blockIdx.x * blockDim.x + threadIdx.x;
    size_t stride = (size_t)gridDim.x * blockDim.x;
    for (size_t i = i0; i < n; i += stride) out[i] = code;
}

// ---------------------------------------------------------------------------
// One-time weight transpose: W f32 [27][in][out] -> WT bf16 [27][out][in]
// grid = 4*27 blocks; LDS-padded transpose, coalesced global read+write.
// ---------------------------------------------------------------------------
__global__ __launch_bounds__(256) void k_wt(
    const float* __restrict__ W0, const float* __restrict__ W1,
    const float* __restrict__ W2, const float* __restrict__ W3,
    bf16* __restrict__ WT)
{
    __shared__ float L[64 * 65];
    int wb = blockIdx.x / 27, k = blockIdx.x % 27;
    const float* src = (wb == 0 ? W0 : wb == 1 ? W1 : wb == 2 ? W2 : W3) + (size_t)k * 4096;
    int tid = threadIdx.x;
    #pragma unroll
    for (int i = 0; i < 16; ++i) {
        int e = i * 256 + tid;              // e = in*64 + out
        L[(e >> 6) * 65 + (e & 63)] = src[e];
    }
    __syncthreads();
    bf16* dst = WT + ((size_t)wb * 27 + k) * 4096;
    #pragma unroll
    for (int i = 0; i < 16; ++i) {
        int e = i * 256 + tid;              // e = out*64 + in
        dst[e] = __float2bfloat16(L[(e & 63) * 65 + (e >> 6)]);
    }
}

// ---------------------------------------------------------------------------
// Stage A: h = prelu(concat(rec_F, bins1_F) @ W_dec + b_dec, a_dec)   [N,64]
// ---------------------------------------------------------------------------
__global__ __launch_bounds__(256) void k_dec(
    const float* __restrict__ rec, const float* __restrict__ bins,
    const float* __restrict__ W, const float* __restrict__ b, const float* __restrict__ a,
    bf16* __restrict__ h, int N)
{
    __shared__ float Wl[72 * 64];
    int tid = threadIdx.x;
    for (int i = tid; i < 72 * 64; i += 256) Wl[i] = W[i];
    int c = tid & 63, w = tid >> 6;
    float bc = b[c];
    float av = a[0];
    __syncthreads();
    int base = blockIdx.x * 32 + w * 8;
    for (int rr = 0; rr < 8; ++rr) {
        int row = base + rr;
        if (row >= N) break;
        float acc = bc;
        float xv[8];
        #pragma unroll
        for (int j8 = 0; j8 < 8; ++j8) {
            load8(rec + (size_t)row * 64 + j8 * 8, xv);
            int j = j8 * 8;
            #pragma unroll
            for (int t = 0; t < 8; ++t) acc += xv[t] * Wl[(j + t) * 64 + c];
        }
        load8(bins + (size_t)row * 8, xv);
        #pragma unroll
        for (int t = 0; t < 8; ++t) acc += xv[t] * Wl[(64 + t) * 64 + c];
        float v = acc >= 0.f ? acc : av * acc;
        h[(size_t)row * 64 + c] = __float2bfloat16(v);
    }
}

// ---------------------------------------------------------------------------
// MFMA sparse 3x3x3 conv. Wave owns G groups of 16 rows. Per k:
//   per-lane validity (rows = lane&15), ballot skip; B-frags = 16B loads from
//   WT[k] (L2); A-frags = gathered 16B x-row slices, invalid lanes zeroed;
//   8x mfma_f32_16x16x32_bf16 per active group -> 16 rows x 64 cols.
// No LDS, no barriers. Fragment maps: A row=lane&15, k=(lane>>4)*8+j;
// C/D col=lane&15, row=(lane>>4)*4+reg (m89/m91-verified).
// ---------------------------------------------------------------------------
template<int G, bool RES, bool OUTF>
__global__ __launch_bounds__(256) void k_sconv_mfma(
    const bf16* __restrict__ x, const int* __restrict__ nbr,
    const bf16* __restrict__ WT,
    const float* __restrict__ bias, const float* __restrict__ a,
    const bf16* __restrict__ res, bf16* __restrict__ out,
    float* __restrict__ outf, int N)
{
    int tid = threadIdx.x;
    int lane = tid & 63;
    int wv = tid >> 6;
    int l15 = lane & 15;
    int lq = lane >> 4;                    // 0..3
    int rowbase = blockIdx.x * (64 * G) + wv * (16 * G);

    f32x4v acc[G][4];
    #pragma unroll
    for (int g = 0; g < G; ++g)
        #pragma unroll
        for (int ct = 0; ct < 4; ++ct) acc[g][ct] = (f32x4v){0.f, 0.f, 0.f, 0.f};

    for (int k = 0; k < 27; ++k) {
        int idx[G];
        int anyl = 0;
        #pragma unroll
        for (int g = 0; g < G; ++g) {
            int row = rowbase + g * 16 + l15;
            idx[g] = (row < N) ? nbr[(size_t)row * 27 + k] : -1;
            anyl |= (idx[g] >= 0) ? 1 : 0;
        }
        if (!__any(anyl)) continue;        // wave-uniform skip

        bf16x8v bfr[4][2];
        const bf16* wk = WT + (size_t)k * 4096;
        #pragma unroll
        for (int ct = 0; ct < 4; ++ct) {
            const bf16* wr = wk + (ct * 16 + l15) * 64 + lq * 8;
            bfr[ct][0] = *reinterpret_cast<const bf16x8v*>(wr);
            bfr[ct][1] = *reinterpret_cast<const bf16x8v*>(wr + 32);
        }
        #pragma unroll
        for (int g = 0; g < G; ++g) {
            if (!__any(idx[g] >= 0)) continue;   // wave-uniform
            bf16x8v a0 = (bf16x8v){0,0,0,0,0,0,0,0};
            bf16x8v a1 = (bf16x8v){0,0,0,0,0,0,0,0};
            if (idx[g] >= 0) {
                const bf16* xr = x + (size_t)idx[g] * 64 + lq * 8;
                a0 = *reinterpret_cast<const bf16x8v*>(xr);
                a1 = *reinterpret_cast<const bf16x8v*>(xr + 32);
            }
            #pragma unroll
            for (int ct = 0; ct < 4; ++ct) {
                acc[g][ct] = __builtin_amdgcn_mfma_f32_16x16x32_bf16(a0, bfr[ct][0], acc[g][ct], 0, 0, 0);
                acc[g][ct] = __builtin_amdgcn_mfma_f32_16x16x32_bf16(a1, bfr[ct][1], acc[g][ct], 0, 0, 0);
            }
        }
    }

    float av = a[0];
    float bs[4];
    #pragma unroll
    for (int ct = 0; ct < 4; ++ct) bs[ct] = bias[ct * 16 + l15];
    #pragma unroll
    for (int g = 0; g < G; ++g) {
        #pragma unroll
        for (int r = 0; r < 4; ++r) {
            int row = rowbase + g * 16 + lq * 4 + r;
            if (row >= N) continue;
            #pragma unroll
            for (int ct = 0; ct < 4; ++ct) {
                int col = ct * 16 + l15;
                float v = acc[g][ct][r] + bs[ct];
                if (RES) v += b2f(res[(size_t)row * 64 + col]);
                v = v >= 0.f ? v : av * v;
                out[(size_t)row * 64 + col] = __float2bfloat16(v);
                if (OUTF) outf[(size_t)row * 64 + col] = v;
            }
        }
    }
}

// ---------------------------------------------------------------------------
// pred[0] linear + bool-mask gather, fused (W: f32 [64,512], L2-resident)
// ---------------------------------------------------------------------------
__global__ __launch_bounds__(256) void k_p0l(
    const bf16* __restrict__ p, const float* __restrict__ W, const float* __restrict__ b,
    const int* __restrict__ pidx, const int* __restrict__ bitj,
    bf16* __restrict__ g, int M)
{
    int tid = threadIdx.x;
    int c = tid & 63, w = tid >> 6;
    int base = blockIdx.x * 32 + w * 8;
    for (int rr = 0; rr < 8; ++rr) {
        int m = base + rr;
        if (m >= M) break;
        int pi = pidx[m];
        int bt = bitj[m];
        int col = bt * 64 + c;
        float acc = b[col];
        float xv[8];
        #pragma unroll
        for (int j8 = 0; j8 < 8; ++j8) {
            load8(p + (size_t)pi * 64 + j8 * 8, xv);
            int j = j8 * 8;
            #pragma unroll
            for (int t = 0; t < 8; ++t)
                acc += xv[t] * W[(size_t)(j + t) * 512 + col];
        }
        g[(size_t)m * 64 + c] = __float2bfloat16(acc);
    }
}

// ---------------------------------------------------------------------------
// loss: logits = q @ Wp1l + b -> log_softmax -> ce/pn -> atomic accum
// ---------------------------------------------------------------------------
__global__ __launch_bounds__(256) void k_loss(
    const bf16* __restrict__ q, const float* __restrict__ W, const float* __restrict__ b,
    const int* __restrict__ bins0, const int* __restrict__ octk,
    const int* __restrict__ ref_batch, const float* __restrict__ pn,
    float* __restrict__ accum, int M)
{
    __shared__ float Wl[64 * 256];
    int tid = threadIdx.x;
    for (int i = tid; i < 64 * 255; i += 256) {
        int j = i / 255, col = i - j * 255;
        Wl[j * 256 + col] = W[i];
    }
    if (tid < 64) Wl[tid * 256 + 255] = 0.f;
    int lane = tid & 63, w = tid >> 6;
    float bcol[4];
    #pragma unroll
    for (int t = 0; t < 4; ++t) {
        int col = lane + 64 * t;
        bcol[t] = (col < 255) ? b[col] : 0.f;
    }
    int ok[8];
    #pragma unroll
    for (int j = 0; j < 8; ++j) ok[j] = octk[j];
    __syncthreads();

    float local = 0.f;
    int waveId = blockIdx.x * 4 + w;
    int nWaves = gridDim.x * 4;
    for (int m = waveId; m < M; m += nWaves) {
        float acc[4] = { bcol[0], bcol[1], bcol[2], bcol[3] };
        float xj[8];
        #pragma unroll
        for (int j8 = 0; j8 < 8; ++j8) {
            load8(q + (size_t)m * 64 + j8 * 8, xj);
            #pragma unroll
            for (int jj = 0; jj < 8; ++jj) {
                int j = j8 * 8 + jj;
                #pragma unroll
                for (int t = 0; t < 4; ++t)
                    acc[t] += xj[jj] * Wl[j * 256 + lane + 64 * t];
            }
        }
        float mx = -1e30f;
        #pragma unroll
        for (int t = 0; t < 4; ++t) {
            int col = lane + 64 * t;
            float v = (col < 255) ? acc[t] : -1e30f;
            mx = fmaxf(mx, v);
        }
        #pragma unroll
        for (int s = 32; s > 0; s >>= 1) mx = fmaxf(mx, __shfl_xor(mx, s, 64));
        float se = 0.f;
        #pragma unroll
        for (int t = 0; t < 4; ++t) {
            int col = lane + 64 * t;
            if (col < 255) se += __expf(acc[t] - mx);
        }
        #pragma unroll
        for (int s = 32; s > 0; s >>= 1) se += __shfl_xor(se, s, 64);
        int oct = 0;
        #pragma unroll
        for (int j = 0; j < 8; ++j) oct += bins0[(size_t)m * 8 + j] << ok[j];
        oct -= 1;
        int tl = oct >> 6, ln = oct & 63;
        float lo = (tl == 0) ? acc[0] : (tl == 1) ? acc[1] : (tl == 2) ? acc[2] : acc[3];
        lo = __shfl(lo, ln, 64);
        float ce = mx + __logf(se) - lo;
        float pnv = pn[ref_batch[m]];
        local += ce / pnv;
    }
    if (lane == 0) atomicAdd(accum, local);
}

__global__ void k_finish(const float* __restrict__ accum, float* __restrict__ outf, int BATCH)
{
    if (threadIdx.x == 0 && blockIdx.x == 0)
        outf[0] = accum[0] * 1.4426950408889634f / (float)BATCH;
}

// ---------------------------------------------------------------------------
// ws: [0,64) header (accum) | buf1, buf2 (M*64 bf16 each) | WT (4*27*4096 bf16)
// ---------------------------------------------------------------------------
extern "C" void kernel_launch(void* const* d_in, const int* in_sizes, int n_in,
                              void* d_out, int out_size, void* d_ws, size_t ws_size,
                              hipStream_t stream)
{
    const float* rec_F   = (const float*)d_in[0];
    const float* bins1_F = (const float*)d_in[1];
    const float* pn      = (const float*)d_in[2];
    const float* W_dec   = (const float*)d_in[3];
    const float* b_dec   = (const float*)d_in[4];
    const float* a_dec   = (const float*)d_in[5];
    const float* Wb1     = (const float*)d_in[6];
    const float* bb1     = (const float*)d_in[7];
    const float* ab1     = (const float*)d_in[8];
    const float* Wb2     = (const float*)d_in[9];
    const float* bb2     = (const float*)d_in[10];
    const float* ab2     = (const float*)d_in[11];
    const float* Wp0c    = (const float*)d_in[12];
    const float* bp0c    = (const float*)d_in[13];
    const float* ap0     = (const float*)d_in[14];
    const float* Wp0l    = (const float*)d_in[15];
    const float* bp0l    = (const float*)d_in[16];
    const float* Wp1c    = (const float*)d_in[17];
    const float* bp1c    = (const float*)d_in[18];
    const float* ap1     = (const float*)d_in[19];
    const float* Wp1l    = (const float*)d_in[20];
    const float* bp1l    = (const float*)d_in[21];
    const int* nbr_rec    = (const int*)d_in[22];
    const int* nbr_child  = (const int*)d_in[23];
    const int* child_pidx = (const int*)d_in[24];
    const int* child_bit  = (const int*)d_in[25];
    const int* bins0      = (const int*)d_in[26];
    const int* oct_kernel = (const int*)d_in[27];
    const int* ref_batch  = (const int*)d_in[28];

    int N = in_sizes[0] / 64;
    int M = in_sizes[24];
    int BATCH = in_sizes[2];

    size_t N64 = (size_t)N * 64, M64 = (size_t)M * 64;
    float* out_y    = (float*)d_out;
    float* out_loss = out_y + N64;

    size_t wt_bytes = (size_t)4 * 27 * 4096 * sizeof(bf16);   // 884736
    size_t required = 64 + 4 * M64 + wt_bytes;
    if (ws_size < required) {
        float code = 200.f + (float)(ws_size >> 20);
        k_code<<<512, 256, 0, stream>>>(out_y, N64, code);
        k_code<<<1, 64, 0, stream>>>(out_loss, 1, code);
        return;
    }

    char* wsb = (char*)d_ws;
    float* accum = (float*)wsb;
    bf16* buf1 = (bf16*)(wsb + 64);
    bf16* buf2 = buf1 + M64;
    bf16* WT   = buf2 + M64;        // [4][27][64][64]
    bf16* WT1 = WT;
    bf16* WT2 = WT + (size_t)27 * 4096;
    bf16* WT3 = WT + (size_t)2 * 27 * 4096;
    bf16* WT4 = WT + (size_t)3 * 27 * 4096;

    hipMemsetAsync(wsb, 0, 64, stream);

    k_wt<<<108, 256, 0, stream>>>(Wb1, Wb2, Wp0c, Wp1c, WT);

    int blocksN32 = (N + 31) / 32;
    int blocksM32 = (M + 31) / 32;
    int blocksN64 = (N + 63) / 64;     // G=1: 64 rows/block
    int blocksM256 = (M + 255) / 256;  // G=4: 256 rows/block

    k_dec<<<blocksN32, 256, 0, stream>>>(rec_F, bins1_F, W_dec, b_dec, a_dec, buf1, N);

    k_sconv_mfma<1, false, false><<<blocksN64, 256, 0, stream>>>(
        buf1, nbr_rec, WT1, bb1, ab1, nullptr, buf2, nullptr, N);

    k_sconv_mfma<1, true, true><<<blocksN64, 256, 0, stream>>>(
        buf2, nbr_rec, WT2, bb2, ab2, buf1, buf1, out_y, N);

    k_sconv_mfma<1, false, false><<<blocksN64, 256, 0, stream>>>(
        buf1, nbr_rec, WT3, bp0c, ap0, nullptr, buf2, nullptr, N);

    k_p0l<<<blocksM32, 256, 0, stream>>>(buf2, Wp0l, bp0l, child_pidx, child_bit, buf1, M);

    k_sconv_mfma<4, false, false><<<blocksM256, 256, 0, stream>>>(
        buf1, nbr_child, WT4, bp1c, ap1, nullptr, buf2, nullptr, M);

    k_loss<<<512, 256, 0, stream>>>(buf2, Wp1l, bp1l, bins0, oct_kernel, ref_batch, pn, accum, M);
    k_finish<<<1, 64, 0, stream>>>(accum, out_loss, BATCH);
}

// Round 11
// 611.133 us; speedup vs baseline: 2.4534x; 1.4328x over previous
//
#include <hip/hip_runtime.h>
#include <hip/hip_bf16.h>

typedef __hip_bfloat16 bf16;
typedef __attribute__((ext_vector_type(8))) short bf16x8v;
typedef __attribute__((ext_vector_type(4))) float f32x4v;

__device__ __forceinline__ float b2f(bf16 v) { return __bfloat162float(v); }
__device__ __forceinline__ float lo16(unsigned int u) {
    union { unsigned int i; float f; } x; x.i = u << 16; return x.f;
}
__device__ __forceinline__ float hi16(unsigned int u) {
    union { unsigned int i; float f; } x; x.i = u & 0xffff0000u; return x.f;
}
template<typename T>
__device__ __forceinline__ void load8(const T* p, float o[8]);
template<>
__device__ __forceinline__ void load8<bf16>(const bf16* p, float o[8]) {
    uint4 v = *reinterpret_cast<const uint4*>(p);
    o[0] = lo16(v.x); o[1] = hi16(v.x);
    o[2] = lo16(v.y); o[3] = hi16(v.y);
    o[4] = lo16(v.z); o[5] = hi16(v.z);
    o[6] = lo16(v.w); o[7] = hi16(v.w);
}
template<>
__device__ __forceinline__ void load8<float>(const float* p, float o[8]) {
    float4 a = reinterpret_cast<const float4*>(p)[0];
    float4 b = reinterpret_cast<const float4*>(p)[1];
    o[0] = a.x; o[1] = a.y; o[2] = a.z; o[3] = a.w;
    o[4] = b.x; o[5] = b.y; o[6] = b.z; o[7] = b.w;
}

__global__ void k_code(float* __restrict__ out, size_t n, float code)
{
    size_t i0 = (size_t)blockIdx.x * blockDim.x + threadIdx.x;
    size_t stride = (size_t)gridDim.x * blockDim.x;
    for (size_t i = i0; i < n; i += stride) out[i] = code;
}

// ---------------------------------------------------------------------------
// One-time conv-weight transpose: W f32 [27][in][out] -> WT bf16 [27][out][in]
// ---------------------------------------------------------------------------
__global__ __launch_bounds__(256) void k_wt(
    const float* __restrict__ W0, const float* __restrict__ W1,
    const float* __restrict__ W2, const float* __restrict__ W3,
    bf16* __restrict__ WT)
{
    __shared__ float L[64 * 65];
    int wb = blockIdx.x / 27, k = blockIdx.x % 27;
    const float* src = (wb == 0 ? W0 : wb == 1 ? W1 : wb == 2 ? W2 : W3) + (size_t)k * 4096;
    int tid = threadIdx.x;
    #pragma unroll
    for (int i = 0; i < 16; ++i) {
        int e = i * 256 + tid;              // e = in*64 + out
        L[(e >> 6) * 65 + (e & 63)] = src[e];
    }
    __syncthreads();
    bf16* dst = WT + ((size_t)wb * 27 + k) * 4096;
    #pragma unroll
    for (int i = 0; i < 16; ++i) {
        int e = i * 256 + tid;              // e = out*64 + in
        dst[e] = __float2bfloat16(L[(e & 63) * 65 + (e >> 6)]);
    }
}

// One-time loss-weight transpose: Wp1l f32 [64][255] -> WT5 bf16 [256][64]
// (row 255 zero-padded). One block, 256 threads: thread = output row (col c).
__global__ __launch_bounds__(256) void k_wt5(
    const float* __restrict__ W, bf16* __restrict__ WT5)
{
    int c = threadIdx.x;
    #pragma unroll
    for (int j = 0; j < 64; ++j) {
        float v = (c < 255) ? W[(size_t)j * 255 + c] : 0.f;
        WT5[(size_t)c * 64 + j] = __float2bfloat16(v);
    }
}

// ---------------------------------------------------------------------------
// Stage A: h = prelu(concat(rec_F, bins1_F) @ W_dec + b_dec, a_dec)   [N,64]
// ---------------------------------------------------------------------------
__global__ __launch_bounds__(256) void k_dec(
    const float* __restrict__ rec, const float* __restrict__ bins,
    const float* __restrict__ W, const float* __restrict__ b, const float* __restrict__ a,
    bf16* __restrict__ h, int N)
{
    __shared__ float Wl[72 * 64];
    int tid = threadIdx.x;
    for (int i = tid; i < 72 * 64; i += 256) Wl[i] = W[i];
    int c = tid & 63, w = tid >> 6;
    float bc = b[c];
    float av = a[0];
    __syncthreads();
    int base = blockIdx.x * 32 + w * 8;
    for (int rr = 0; rr < 8; ++rr) {
        int row = base + rr;
        if (row >= N) break;
        float acc = bc;
        float xv[8];
        #pragma unroll
        for (int j8 = 0; j8 < 8; ++j8) {
            load8(rec + (size_t)row * 64 + j8 * 8, xv);
            int j = j8 * 8;
            #pragma unroll
            for (int t = 0; t < 8; ++t) acc += xv[t] * Wl[(j + t) * 64 + c];
        }
        load8(bins + (size_t)row * 8, xv);
        #pragma unroll
        for (int t = 0; t < 8; ++t) acc += xv[t] * Wl[(64 + t) * 64 + c];
        float v = acc >= 0.f ? acc : av * acc;
        h[(size_t)row * 64 + c] = __float2bfloat16(v);
    }
}

// ---------------------------------------------------------------------------
// MFMA sparse 3x3x3 conv (verified round 10). Wave owns G groups of 16 rows.
// ---------------------------------------------------------------------------
template<int G, bool RES, bool OUTF>
__global__ __launch_bounds__(256) void k_sconv_mfma(
    const bf16* __restrict__ x, const int* __restrict__ nbr,
    const bf16* __restrict__ WT,
    const float* __restrict__ bias, const float* __restrict__ a,
    const bf16* __restrict__ res, bf16* __restrict__ out,
    float* __restrict__ outf, int N)
{
    int tid = threadIdx.x;
    int lane = tid & 63;
    int wv = tid >> 6;
    int l15 = lane & 15;
    int lq = lane >> 4;                    // 0..3
    int rowbase = blockIdx.x * (64 * G) + wv * (16 * G);

    f32x4v acc[G][4];
    #pragma unroll
    for (int g = 0; g < G; ++g)
        #pragma unroll
        for (int ct = 0; ct < 4; ++ct) acc[g][ct] = (f32x4v){0.f, 0.f, 0.f, 0.f};

    for (int k = 0; k < 27; ++k) {
        int idx[G];
        int anyl = 0;
        #pragma unroll
        for (int g = 0; g < G; ++g) {
            int row = rowbase + g * 16 + l15;
            idx[g] = (row < N) ? nbr[(size_t)row * 27 + k] : -1;
            anyl |= (idx[g] >= 0) ? 1 : 0;
        }
        if (!__any(anyl)) continue;        // wave-uniform skip

        bf16x8v bfr[4][2];
        const bf16* wk = WT + (size_t)k * 4096;
        #pragma unroll
        for (int ct = 0; ct < 4; ++ct) {
            const bf16* wr = wk + (ct * 16 + l15) * 64 + lq * 8;
            bfr[ct][0] = *reinterpret_cast<const bf16x8v*>(wr);
            bfr[ct][1] = *reinterpret_cast<const bf16x8v*>(wr + 32);
        }
        #pragma unroll
        for (int g = 0; g < G; ++g) {
            if (!__any(idx[g] >= 0)) continue;   // wave-uniform
            bf16x8v a0 = (bf16x8v){0,0,0,0,0,0,0,0};
            bf16x8v a1 = (bf16x8v){0,0,0,0,0,0,0,0};
            if (idx[g] >= 0) {
                const bf16* xr = x + (size_t)idx[g] * 64 + lq * 8;
                a0 = *reinterpret_cast<const bf16x8v*>(xr);
                a1 = *reinterpret_cast<const bf16x8v*>(xr + 32);
            }
            #pragma unroll
            for (int ct = 0; ct < 4; ++ct) {
                acc[g][ct] = __builtin_amdgcn_mfma_f32_16x16x32_bf16(a0, bfr[ct][0], acc[g][ct], 0, 0, 0);
                acc[g][ct] = __builtin_amdgcn_mfma_f32_16x16x32_bf16(a1, bfr[ct][1], acc[g][ct], 0, 0, 0);
            }
        }
    }

    float av = a[0];
    float bs[4];
    #pragma unroll
    for (int ct = 0; ct < 4; ++ct) bs[ct] = bias[ct * 16 + l15];
    #pragma unroll
    for (int g = 0; g < G; ++g) {
        #pragma unroll
        for (int r = 0; r < 4; ++r) {
            int row = rowbase + g * 16 + lq * 4 + r;
            if (row >= N) continue;
            #pragma unroll
            for (int ct = 0; ct < 4; ++ct) {
                int col = ct * 16 + l15;
                float v = acc[g][ct][r] + bs[ct];
                if (RES) v += b2f(res[(size_t)row * 64 + col]);
                v = v >= 0.f ? v : av * v;
                out[(size_t)row * 64 + col] = __float2bfloat16(v);
                if (OUTF) outf[(size_t)row * 64 + col] = v;
            }
        }
    }
}

// ---------------------------------------------------------------------------
// pred[0] linear + bool-mask gather, fused (W: f32 [64,512], L2-resident)
// ---------------------------------------------------------------------------
__global__ __launch_bounds__(256) void k_p0l(
    const bf16* __restrict__ p, const float* __restrict__ W, const float* __restrict__ b,
    const int* __restrict__ pidx, const int* __restrict__ bitj,
    bf16* __restrict__ g, int M)
{
    int tid = threadIdx.x;
    int c = tid & 63, w = tid >> 6;
    int base = blockIdx.x * 32 + w * 8;
    for (int rr = 0; rr < 8; ++rr) {
        int m = base + rr;
        if (m >= M) break;
        int pi = pidx[m];
        int bt = bitj[m];
        int col = bt * 64 + c;
        float acc = b[col];
        float xv[8];
        #pragma unroll
        for (int j8 = 0; j8 < 8; ++j8) {
            load8(p + (size_t)pi * 64 + j8 * 8, xv);
            int j = j8 * 8;
            #pragma unroll
            for (int t = 0; t < 8; ++t)
                acc += xv[t] * W[(size_t)(j + t) * 512 + col];
        }
        g[(size_t)m * 64 + c] = __float2bfloat16(acc);
    }
}

// ---------------------------------------------------------------------------
// MFMA loss: logits[16 rows x 256 cols] per wave via 32 MFMAs; in-register
// softmax per 16-lane group; ce/pn atomically accumulated.
// A: row=lane&15, k=(lane>>4)*8+j ; C/D: col=lane&15, row=(lane>>4)*4+r.
// B-frags (WT5, 16 col-tiles) hoisted into regs once per thread.
// ---------------------------------------------------------------------------
__global__ __launch_bounds__(256) void k_loss_mfma(
    const bf16* __restrict__ q, const bf16* __restrict__ WT5,
    const float* __restrict__ b,
    const int* __restrict__ bins0, const int* __restrict__ octk,
    const int* __restrict__ ref_batch, const float* __restrict__ pn,
    float* __restrict__ accum, int M)
{
    int tid = threadIdx.x;
    int lane = tid & 63;
    int wv = tid >> 6;
    int l15 = lane & 15;
    int lq = lane >> 4;

    // hoist B fragments: 16 col-tiles x 2 k-frags
    bf16x8v bfr[16][2];
    #pragma unroll
    for (int ct = 0; ct < 16; ++ct) {
        const bf16* wr = WT5 + (size_t)(ct * 16 + l15) * 64 + lq * 8;
        bfr[ct][0] = *reinterpret_cast<const bf16x8v*>(wr);
        bfr[ct][1] = *reinterpret_cast<const bf16x8v*>(wr + 32);
    }
    float bs[16];
    #pragma unroll
    for (int ct = 0; ct < 16; ++ct) bs[ct] = (ct * 16 + l15 < 255) ? b[ct * 16 + l15] : 0.f;
    int ok[8];
    #pragma unroll
    for (int j = 0; j < 8; ++j) ok[j] = octk[j];

    float local = 0.f;
    int tiles = (M + 15) / 16;
    int waveId = blockIdx.x * 4 + wv;
    int nWaves = gridDim.x * 4;

    for (int t = waveId; t < tiles; t += nWaves) {
        int rowbase = t * 16;
        // A fragments
        int arow = rowbase + l15;
        bf16x8v a0 = (bf16x8v){0,0,0,0,0,0,0,0};
        bf16x8v a1 = (bf16x8v){0,0,0,0,0,0,0,0};
        if (arow < M) {
            const bf16* xr = q + (size_t)arow * 64 + lq * 8;
            a0 = *reinterpret_cast<const bf16x8v*>(xr);
            a1 = *reinterpret_cast<const bf16x8v*>(xr + 32);
        }
        f32x4v acc[16];
        #pragma unroll
        for (int ct = 0; ct < 16; ++ct) {
            f32x4v z = (f32x4v){0.f, 0.f, 0.f, 0.f};
            z = __builtin_amdgcn_mfma_f32_16x16x32_bf16(a0, bfr[ct][0], z, 0, 0, 0);
            z = __builtin_amdgcn_mfma_f32_16x16x32_bf16(a1, bfr[ct][1], z, 0, 0, 0);
            acc[ct] = z;
        }
        // bias; col 255 handled by exclusion below
        #pragma unroll
        for (int ct = 0; ct < 16; ++ct) {
            #pragma unroll
            for (int r = 0; r < 4; ++r) acc[ct][r] += bs[ct];
        }
        // per element r: group lq owns row rowbase + lq*4 + r
        #pragma unroll
        for (int r = 0; r < 4; ++r) {
            int row = rowbase + lq * 4 + r;
            bool rv = (row < M);
            int rowc = rv ? row : 0;
            // max over this lane's 16 cols (col 255 excluded)
            float mx = -1e30f;
            #pragma unroll
            for (int ct = 0; ct < 16; ++ct) {
                float v = acc[ct][r];
                if (ct == 15 && l15 == 15) v = -1e30f;
                mx = fmaxf(mx, v);
            }
            #pragma unroll
            for (int s = 1; s < 16; s <<= 1) mx = fmaxf(mx, __shfl_xor(mx, s, 64));
            float se = 0.f;
            #pragma unroll
            for (int ct = 0; ct < 16; ++ct) {
                if (ct == 15 && l15 == 15) continue;
                se += __expf(acc[ct][r] - mx);
            }
            #pragma unroll
            for (int s = 1; s < 16; s <<= 1) se += __shfl_xor(se, s, 64);
            // target logit
            int oct = 0;
            #pragma unroll
            for (int j = 0; j < 8; ++j) oct += bins0[(size_t)rowc * 8 + j] << ok[j];
            oct -= 1;                         // group-uniform, in [0,254]
            int cts = oct >> 4;
            float cand = acc[0][r];
            #pragma unroll
            for (int ct = 1; ct < 16; ++ct) cand = (cts == ct) ? acc[ct][r] : cand;
            float lo = __shfl(cand, lq * 16 + (oct & 15), 64);
            if (rv && l15 == 0) {
                float ce = mx + __logf(se) - lo;
                local += ce / pn[ref_batch[row]];
            }
        }
    }
    #pragma unroll
    for (int s = 32; s > 0; s >>= 1) local += __shfl_xor(local, s, 64);
    if (lane == 0) atomicAdd(accum, local);
}

__global__ void k_finish(const float* __restrict__ accum, float* __restrict__ outf, int BATCH)
{
    if (threadIdx.x == 0 && blockIdx.x == 0)
        outf[0] = accum[0] * 1.4426950408889634f / (float)BATCH;
}

// ---------------------------------------------------------------------------
// ws: [0,64) accum | buf1,buf2 (M*64 bf16) | WT (4*27*4096 bf16) | WT5 (256*64 bf16)
// ---------------------------------------------------------------------------
extern "C" void kernel_launch(void* const* d_in, const int* in_sizes, int n_in,
                              void* d_out, int out_size, void* d_ws, size_t ws_size,
                              hipStream_t stream)
{
    const float* rec_F   = (const float*)d_in[0];
    const float* bins1_F = (const float*)d_in[1];
    const float* pn      = (const float*)d_in[2];
    const float* W_dec   = (const float*)d_in[3];
    const float* b_dec   = (const float*)d_in[4];
    const float* a_dec   = (const float*)d_in[5];
    const float* Wb1     = (const float*)d_in[6];
    const float* bb1     = (const float*)d_in[7];
    const float* ab1     = (const float*)d_in[8];
    const float* Wb2     = (const float*)d_in[9];
    const float* bb2     = (const float*)d_in[10];
    const float* ab2     = (const float*)d_in[11];
    const float* Wp0c    = (const float*)d_in[12];
    const float* bp0c    = (const float*)d_in[13];
    const float* ap0     = (const float*)d_in[14];
    const float* Wp0l    = (const float*)d_in[15];
    const float* bp0l    = (const float*)d_in[16];
    const float* Wp1c    = (const float*)d_in[17];
    const float* bp1c    = (const float*)d_in[18];
    const float* ap1     = (const float*)d_in[19];
    const float* Wp1l    = (const float*)d_in[20];
    const float* bp1l    = (const float*)d_in[21];
    const int* nbr_rec    = (const int*)d_in[22];
    const int* nbr_child  = (const int*)d_in[23];
    const int* child_pidx = (const int*)d_in[24];
    const int* child_bit  = (const int*)d_in[25];
    const int* bins0      = (const int*)d_in[26];
    const int* oct_kernel = (const int*)d_in[27];
    const int* ref_batch  = (const int*)d_in[28];

    int N = in_sizes[0] / 64;
    int M = in_sizes[24];
    int BATCH = in_sizes[2];

    size_t N64 = (size_t)N * 64, M64 = (size_t)M * 64;
    float* out_y    = (float*)d_out;
    float* out_loss = out_y + N64;

    size_t wt_bytes  = (size_t)4 * 27 * 4096 * sizeof(bf16);   // 884736
    size_t wt5_bytes = (size_t)256 * 64 * sizeof(bf16);        // 32768
    size_t required = 64 + 4 * M64 + wt_bytes + wt5_bytes;
    if (ws_size < required) {
        float code = 200.f + (float)(ws_size >> 20);
        k_code<<<512, 256, 0, stream>>>(out_y, N64, code);
        k_code<<<1, 64, 0, stream>>>(out_loss, 1, code);
        return;
    }

    char* wsb = (char*)d_ws;
    float* accum = (float*)wsb;
    bf16* buf1 = (bf16*)(wsb + 64);
    bf16* buf2 = buf1 + M64;
    bf16* WT   = buf2 + M64;        // [4][27][64][64]
    bf16* WT1 = WT;
    bf16* WT2 = WT + (size_t)27 * 4096;
    bf16* WT3 = WT + (size_t)2 * 27 * 4096;
    bf16* WT4 = WT + (size_t)3 * 27 * 4096;
    bf16* WT5 = WT + (size_t)4 * 27 * 4096;   // [256][64]

    hipMemsetAsync(wsb, 0, 64, stream);

    k_wt<<<108, 256, 0, stream>>>(Wb1, Wb2, Wp0c, Wp1c, WT);
    k_wt5<<<1, 256, 0, stream>>>(Wp1l, WT5);

    int blocksN32 = (N + 31) / 32;
    int blocksM32 = (M + 31) / 32;
    int blocksN64 = (N + 63) / 64;     // G=1: 64 rows/block
    int blocksM256 = (M + 255) / 256;  // G=4: 256 rows/block

    k_dec<<<blocksN32, 256, 0, stream>>>(rec_F, bins1_F, W_dec, b_dec, a_dec, buf1, N);

    k_sconv_mfma<1, false, false><<<blocksN64, 256, 0, stream>>>(
        buf1, nbr_rec, WT1, bb1, ab1, nullptr, buf2, nullptr, N);

    k_sconv_mfma<1, true, true><<<blocksN64, 256, 0, stream>>>(
        buf2, nbr_rec, WT2, bb2, ab2, buf1, buf1, out_y, N);

    k_sconv_mfma<1, false, false><<<blocksN64, 256, 0, stream>>>(
        buf1, nbr_rec, WT3, bp0c, ap0, nullptr, buf2, nullptr, N);

    k_p0l<<<blocksM32, 256, 0, stream>>>(buf2, Wp0l, bp0l, child_pidx, child_bit, buf1, M);

    k_sconv_mfma<4, false, false><<<blocksM256, 256, 0, stream>>>(
        buf1, nbr_child, WT4, bp1c, ap1, nullptr, buf2, nullptr, M);

    k_loss_mfma<<<1024, 256, 0, stream>>>(buf2, WT5, bp1l, bins0, oct_kernel,
                                          ref_batch, pn, accum, M);
    k_finish<<<1, 64, 0, stream>>>(accum, out_loss, BATCH);
}

// Round 13
// 585.729 us; speedup vs baseline: 2.5598x; 1.0434x over previous
//
#include <hip/hip_runtime.h>
#include <hip/hip_bf16.h>

typedef __hip_bfloat16 bf16;
typedef __attribute__((ext_vector_type(8))) short bf16x8v;
typedef __attribute__((ext_vector_type(4))) float f32x4v;

__device__ __forceinline__ float b2f(bf16 v) { return __bfloat162float(v); }
__device__ __forceinline__ float lo16(unsigned int u) {
    union { unsigned int i; float f; } x; x.i = u << 16; return x.f;
}
__device__ __forceinline__ float hi16(unsigned int u) {
    union { unsigned int i; float f; } x; x.i = u & 0xffff0000u; return x.f;
}
template<typename T>
__device__ __forceinline__ void load8(const T* p, float o[8]);
template<>
__device__ __forceinline__ void load8<bf16>(const bf16* p, float o[8]) {
    uint4 v = *reinterpret_cast<const uint4*>(p);
    o[0] = lo16(v.x); o[1] = hi16(v.x);
    o[2] = lo16(v.y); o[3] = hi16(v.y);
    o[4] = lo16(v.z); o[5] = hi16(v.z);
    o[6] = lo16(v.w); o[7] = hi16(v.w);
}
template<>
__device__ __forceinline__ void load8<float>(const float* p, float o[8]) {
    float4 a = reinterpret_cast<const float4*>(p)[0];
    float4 b = reinterpret_cast<const float4*>(p)[1];
    o[0] = a.x; o[1] = a.y; o[2] = a.z; o[3] = a.w;
    o[4] = b.x; o[5] = b.y; o[6] = b.z; o[7] = b.w;
}

__global__ void k_code(float* __restrict__ out, size_t n, float code)
{
    size_t i0 = (size_t)blockIdx.x * blockDim.x + threadIdx.x;
    size_t stride = (size_t)gridDim.x * blockDim.x;
    for (size_t i = i0; i < n; i += stride) out[i] = code;
}

// ---------------------------------------------------------------------------
// One-time conv-weight transpose: W f32 [27][in][out] -> WT bf16 [27][out][in]
// ---------------------------------------------------------------------------
__global__ __launch_bounds__(256) void k_wt(
    const float* __restrict__ W0, const float* __restrict__ W1,
    const float* __restrict__ W2, const float* __restrict__ W3,
    bf16* __restrict__ WT)
{
    __shared__ float L[64 * 65];
    int wb = blockIdx.x / 27, k = blockIdx.x % 27;
    const float* src = (wb == 0 ? W0 : wb == 1 ? W1 : wb == 2 ? W2 : W3) + (size_t)k * 4096;
    int tid = threadIdx.x;
    #pragma unroll
    for (int i = 0; i < 16; ++i) {
        int e = i * 256 + tid;              // e = in*64 + out
        L[(e >> 6) * 65 + (e & 63)] = src[e];
    }
    __syncthreads();
    bf16* dst = WT + ((size_t)wb * 27 + k) * 4096;
    #pragma unroll
    for (int i = 0; i < 16; ++i) {
        int e = i * 256 + tid;              // e = out*64 + in
        dst[e] = __float2bfloat16(L[(e & 63) * 65 + (e >> 6)]);
    }
}

// One-time loss-weight transpose: Wp1l f32 [64][255] -> WT5 bf16 [256][64]
__global__ __launch_bounds__(256) void k_wt5(
    const float* __restrict__ W, bf16* __restrict__ WT5)
{
    int c = threadIdx.x;
    #pragma unroll
    for (int j = 0; j < 64; ++j) {
        float v = (c < 255) ? W[(size_t)j * 255 + c] : 0.f;
        WT5[(size_t)c * 64 + j] = __float2bfloat16(v);
    }
}

// One-time p0l-weight transpose: Wp0l f32 [64][512] -> WTP bf16 [8][out64][in64]
__global__ __launch_bounds__(256) void k_wtp(
    const float* __restrict__ W, bf16* __restrict__ WTP)
{
    __shared__ float L[64 * 65];
    int bt = blockIdx.x;
    int tid = threadIdx.x;
    #pragma unroll
    for (int i = 0; i < 16; ++i) {
        int e = i * 256 + tid;              // e = in*64 + out
        L[(e >> 6) * 65 + (e & 63)] = W[(size_t)(e >> 6) * 512 + bt * 64 + (e & 63)];
    }
    __syncthreads();
    bf16* dst = WTP + (size_t)bt * 4096;
    #pragma unroll
    for (int i = 0; i < 16; ++i) {
        int e = i * 256 + tid;              // e = out*64 + in
        dst[e] = __float2bfloat16(L[(e & 63) * 65 + (e >> 6)]);
    }
}

// ---------------------------------------------------------------------------
// Stage A: h = prelu(concat(rec_F, bins1_F) @ W_dec + b_dec, a_dec)   [N,64]
// ---------------------------------------------------------------------------
__global__ __launch_bounds__(256) void k_dec(
    const float* __restrict__ rec, const float* __restrict__ bins,
    const float* __restrict__ W, const float* __restrict__ b, const float* __restrict__ a,
    bf16* __restrict__ h, int N)
{
    __shared__ float Wl[72 * 64];
    int tid = threadIdx.x;
    for (int i = tid; i < 72 * 64; i += 256) Wl[i] = W[i];
    int c = tid & 63, w = tid >> 6;
    float bc = b[c];
    float av = a[0];
    __syncthreads();
    int base = blockIdx.x * 32 + w * 8;
    for (int rr = 0; rr < 8; ++rr) {
        int row = base + rr;
        if (row >= N) break;
        float acc = bc;
        float xv[8];
        #pragma unroll
        for (int j8 = 0; j8 < 8; ++j8) {
            load8(rec + (size_t)row * 64 + j8 * 8, xv);
            int j = j8 * 8;
            #pragma unroll
            for (int t = 0; t < 8; ++t) acc += xv[t] * Wl[(j + t) * 64 + c];
        }
        load8(bins + (size_t)row * 8, xv);
        #pragma unroll
        for (int t = 0; t < 8; ++t) acc += xv[t] * Wl[(64 + t) * 64 + c];
        float v = acc >= 0.f ? acc : av * acc;
        h[(size_t)row * 64 + c] = __float2bfloat16(v);
    }
}

// ---------------------------------------------------------------------------
// MFMA sparse 3x3x3 conv (verified round 10). Wave owns G groups of 16 rows.
// res/out may alias (same element, same thread: read-then-write).
// ---------------------------------------------------------------------------
template<int G, bool RES, bool OUTF>
__global__ __launch_bounds__(256) void k_sconv_mfma(
    const bf16* __restrict__ x, const int* __restrict__ nbr,
    const bf16* __restrict__ WT,
    const float* __restrict__ bias, const float* __restrict__ a,
    const bf16* res, bf16* out,
    float* __restrict__ outf, int N)
{
    int tid = threadIdx.x;
    int lane = tid & 63;
    int wv = tid >> 6;
    int l15 = lane & 15;
    int lq = lane >> 4;                    // 0..3
    int rowbase = blockIdx.x * (64 * G) + wv * (16 * G);

    f32x4v acc[G][4];
    #pragma unroll
    for (int g = 0; g < G; ++g)
        #pragma unroll
        for (int ct = 0; ct < 4; ++ct) acc[g][ct] = (f32x4v){0.f, 0.f, 0.f, 0.f};

    for (int k = 0; k < 27; ++k) {
        int idx[G];
        int anyl = 0;
        #pragma unroll
        for (int g = 0; g < G; ++g) {
            int row = rowbase + g * 16 + l15;
            idx[g] = (row < N) ? nbr[(size_t)row * 27 + k] : -1;
            anyl |= (idx[g] >= 0) ? 1 : 0;
        }
        if (!__any(anyl)) continue;        // wave-uniform skip

        bf16x8v bfr[4][2];
        const bf16* wk = WT + (size_t)k * 4096;
        #pragma unroll
        for (int ct = 0; ct < 4; ++ct) {
            const bf16* wr = wk + (ct * 16 + l15) * 64 + lq * 8;
            bfr[ct][0] = *reinterpret_cast<const bf16x8v*>(wr);
            bfr[ct][1] = *reinterpret_cast<const bf16x8v*>(wr + 32);
        }
        #pragma unroll
        for (int g = 0; g < G; ++g) {
            if (!__any(idx[g] >= 0)) continue;   // wave-uniform
            bf16x8v a0 = (bf16x8v){0,0,0,0,0,0,0,0};
            bf16x8v a1 = (bf16x8v){0,0,0,0,0,0,0,0};
            if (idx[g] >= 0) {
                const bf16* xr = x + (size_t)idx[g] * 64 + lq * 8;
                a0 = *reinterpret_cast<const bf16x8v*>(xr);
                a1 = *reinterpret_cast<const bf16x8v*>(xr + 32);
            }
            #pragma unroll
            for (int ct = 0; ct < 4; ++ct) {
                acc[g][ct] = __builtin_amdgcn_mfma_f32_16x16x32_bf16(a0, bfr[ct][0], acc[g][ct], 0, 0, 0);
                acc[g][ct] = __builtin_amdgcn_mfma_f32_16x16x32_bf16(a1, bfr[ct][1], acc[g][ct], 0, 0, 0);
            }
        }
    }

    float av = a[0];
    float bs[4];
    #pragma unroll
    for (int ct = 0; ct < 4; ++ct) bs[ct] = bias[ct * 16 + l15];
    #pragma unroll
    for (int g = 0; g < G; ++g) {
        #pragma unroll
        for (int r = 0; r < 4; ++r) {
            int row = rowbase + g * 16 + lq * 4 + r;
            if (row >= N) continue;
            #pragma unroll
            for (int ct = 0; ct < 4; ++ct) {
                int col = ct * 16 + l15;
                float v = acc[g][ct][r] + bs[ct];
                if (RES) v += b2f(res[(size_t)row * 64 + col]);
                v = v >= 0.f ? v : av * v;
                out[(size_t)row * 64 + col] = __float2bfloat16(v);
                if (OUTF) outf[(size_t)row * 64 + col] = v;
            }
        }
    }
}

// ---------------------------------------------------------------------------
// MFMA p0l gather-linear: g[m] = p[pidx[m]] @ Wblk[bitj[m]] + bp0l[bitj[m]*64+..]
// ---------------------------------------------------------------------------
__global__ __launch_bounds__(256) void k_p0l_mfma(
    const bf16* __restrict__ p, const bf16* __restrict__ WTP,
    const float* __restrict__ b,
    const int* __restrict__ pidx, const int* __restrict__ bitj,
    bf16* __restrict__ g, int M)
{
    int tid = threadIdx.x;
    int lane = tid & 63;
    int wv = tid >> 6;
    int l15 = lane & 15;
    int lq = lane >> 4;
    int tiles = (M + 15) / 16;
    int waveId = blockIdx.x * 4 + wv;
    int nWaves = gridDim.x * 4;
    const bf16x8v zv = (bf16x8v){0,0,0,0,0,0,0,0};

    for (int t = waveId; t < tiles; t += nWaves) {
        int rowbase = t * 16;
        int m = rowbase + l15;
        bool mv = (m < M);
        int pi = mv ? pidx[m] : 0;
        int bt = mv ? bitj[m] : -1;
        bf16x8v a0 = zv, a1 = zv;
        if (mv) {
            const bf16* xr = p + (size_t)pi * 64 + lq * 8;
            a0 = *reinterpret_cast<const bf16x8v*>(xr);
            a1 = *reinterpret_cast<const bf16x8v*>(xr + 32);
        }
        f32x4v acc[4];
        #pragma unroll
        for (int ct = 0; ct < 4; ++ct) acc[ct] = (f32x4v){0.f, 0.f, 0.f, 0.f};

        #pragma unroll
        for (int b8 = 0; b8 < 8; ++b8) {
            if (!__any(bt == b8)) continue;   // wave-uniform skip
            bf16x8v m0 = (bt == b8) ? a0 : zv;
            bf16x8v m1 = (bt == b8) ? a1 : zv;
            const bf16* wk = WTP + (size_t)b8 * 4096;
            #pragma unroll
            for (int ct = 0; ct < 4; ++ct) {
                const bf16* wr = wk + (ct * 16 + l15) * 64 + lq * 8;
                bf16x8v b0 = *reinterpret_cast<const bf16x8v*>(wr);
                bf16x8v b1 = *reinterpret_cast<const bf16x8v*>(wr + 32);
                acc[ct] = __builtin_amdgcn_mfma_f32_16x16x32_bf16(m0, b0, acc[ct], 0, 0, 0);
                acc[ct] = __builtin_amdgcn_mfma_f32_16x16x32_bf16(m1, b1, acc[ct], 0, 0, 0);
            }
        }
        #pragma unroll
        for (int r = 0; r < 4; ++r) {
            int row = rowbase + lq * 4 + r;
            if (row >= M) continue;
            int btr = bitj[row];
            #pragma unroll
            for (int ct = 0; ct < 4; ++ct) {
                int col = ct * 16 + l15;
                float v = acc[ct][r] + b[btr * 64 + col];
                g[(size_t)row * 64 + col] = __float2bfloat16(v);
            }
        }
    }
}

// ---------------------------------------------------------------------------
// MFMA loss (verified round 11)
// ---------------------------------------------------------------------------
__global__ __launch_bounds__(256) void k_loss_mfma(
    const bf16* __restrict__ q, const bf16* __restrict__ WT5,
    const float* __restrict__ b,
    const int* __restrict__ bins0, const int* __restrict__ octk,
    const int* __restrict__ ref_batch, const float* __restrict__ pn,
    float* __restrict__ accum, int M)
{
    int tid = threadIdx.x;
    int lane = tid & 63;
    int wv = tid >> 6;
    int l15 = lane & 15;
    int lq = lane >> 4;

    bf16x8v bfr[16][2];
    #pragma unroll
    for (int ct = 0; ct < 16; ++ct) {
        const bf16* wr = WT5 + (size_t)(ct * 16 + l15) * 64 + lq * 8;
        bfr[ct][0] = *reinterpret_cast<const bf16x8v*>(wr);
        bfr[ct][1] = *reinterpret_cast<const bf16x8v*>(wr + 32);
    }
    float bs[16];
    #pragma unroll
    for (int ct = 0; ct < 16; ++ct) bs[ct] = (ct * 16 + l15 < 255) ? b[ct * 16 + l15] : 0.f;
    int ok[8];
    #pragma unroll
    for (int j = 0; j < 8; ++j) ok[j] = octk[j];

    float local = 0.f;
    int tiles = (M + 15) / 16;
    int waveId = blockIdx.x * 4 + wv;
    int nWaves = gridDim.x * 4;

    for (int t = waveId; t < tiles; t += nWaves) {
        int rowbase = t * 16;
        int arow = rowbase + l15;
        bf16x8v a0 = (bf16x8v){0,0,0,0,0,0,0,0};
        bf16x8v a1 = (bf16x8v){0,0,0,0,0,0,0,0};
        if (arow < M) {
            const bf16* xr = q + (size_t)arow * 64 + lq * 8;
            a0 = *reinterpret_cast<const bf16x8v*>(xr);
            a1 = *reinterpret_cast<const bf16x8v*>(xr + 32);
        }
        f32x4v acc[16];
        #pragma unroll
        for (int ct = 0; ct < 16; ++ct) {
            f32x4v z = (f32x4v){0.f, 0.f, 0.f, 0.f};
            z = __builtin_amdgcn_mfma_f32_16x16x32_bf16(a0, bfr[ct][0], z, 0, 0, 0);
            z = __builtin_amdgcn_mfma_f32_16x16x32_bf16(a1, bfr[ct][1], z, 0, 0, 0);
            acc[ct] = z;
        }
        #pragma unroll
        for (int ct = 0; ct < 16; ++ct) {
            #pragma unroll
            for (int r = 0; r < 4; ++r) acc[ct][r] += bs[ct];
        }
        #pragma unroll
        for (int r = 0; r < 4; ++r) {
            int row = rowbase + lq * 4 + r;
            bool rv = (row < M);
            int rowc = rv ? row : 0;
            float mx = -1e30f;
            #pragma unroll
            for (int ct = 0; ct < 16; ++ct) {
                float v = acc[ct][r];
                if (ct == 15 && l15 == 15) v = -1e30f;
                mx = fmaxf(mx, v);
            }
            #pragma unroll
            for (int s = 1; s < 16; s <<= 1) mx = fmaxf(mx, __shfl_xor(mx, s, 64));
            float se = 0.f;
            #pragma unroll
            for (int ct = 0; ct < 16; ++ct) {
                if (ct == 15 && l15 == 15) continue;
                se += __expf(acc[ct][r] - mx);
            }
            #pragma unroll
            for (int s = 1; s < 16; s <<= 1) se += __shfl_xor(se, s, 64);
            int oct = 0;
            #pragma unroll
            for (int j = 0; j < 8; ++j) oct += bins0[(size_t)rowc * 8 + j] << ok[j];
            oct -= 1;
            int cts = oct >> 4;
            float cand = acc[0][r];
            #pragma unroll
            for (int ct = 1; ct < 16; ++ct) cand = (cts == ct) ? acc[ct][r] : cand;
            float lo = __shfl(cand, lq * 16 + (oct & 15), 64);
            if (rv && l15 == 0) {
                float ce = mx + __logf(se) - lo;
                local += ce / pn[ref_batch[row]];
            }
        }
    }
    #pragma unroll
    for (int s = 32; s > 0; s >>= 1) local += __shfl_xor(local, s, 64);
    if (lane == 0) atomicAdd(accum, local);
}

__global__ void k_finish(const float* __restrict__ accum, float* __restrict__ outf, int BATCH)
{
    if (threadIdx.x == 0 && blockIdx.x == 0)
        outf[0] = accum[0] * 1.4426950408889634f / (float)BATCH;
}

// ---------------------------------------------------------------------------
// ws: [0,64) accum | buf1,buf2 (M*64 bf16 each) | yf (N*64 f32) |
//     WT(4*27*4096 bf16) | WT5(256*64) | WTP(8*4096)
// y is staged in yf and published to d_out LAST (hipMemcpyAsync D2D) so no
// later dispatch can corrupt d_out (round-12 post-timing divergence defense).
// ---------------------------------------------------------------------------
extern "C" void kernel_launch(void* const* d_in, const int* in_sizes, int n_in,
                              void* d_out, int out_size, void* d_ws, size_t ws_size,
                              hipStream_t stream)
{
    const float* rec_F   = (const float*)d_in[0];
    const float* bins1_F = (const float*)d_in[1];
    const float* pn      = (const float*)d_in[2];
    const float* W_dec   = (const float*)d_in[3];
    const float* b_dec   = (const float*)d_in[4];
    const float* a_dec   = (const float*)d_in[5];
    const float* Wb1     = (const float*)d_in[6];
    const float* bb1     = (const float*)d_in[7];
    const float* ab1     = (const float*)d_in[8];
    const float* Wb2     = (const float*)d_in[9];
    const float* bb2     = (const float*)d_in[10];
    const float* ab2     = (const float*)d_in[11];
    const float* Wp0c    = (const float*)d_in[12];
    const float* bp0c    = (const float*)d_in[13];
    const float* ap0     = (const float*)d_in[14];
    const float* Wp0l    = (const float*)d_in[15];
    const float* bp0l    = (const float*)d_in[16];
    const float* Wp1c    = (const float*)d_in[17];
    const float* bp1c    = (const float*)d_in[18];
    const float* ap1     = (const float*)d_in[19];
    const float* Wp1l    = (const float*)d_in[20];
    const float* bp1l    = (const float*)d_in[21];
    const int* nbr_rec    = (const int*)d_in[22];
    const int* nbr_child  = (const int*)d_in[23];
    const int* child_pidx = (const int*)d_in[24];
    const int* child_bit  = (const int*)d_in[25];
    const int* bins0      = (const int*)d_in[26];
    const int* oct_kernel = (const int*)d_in[27];
    const int* ref_batch  = (const int*)d_in[28];

    int N = in_sizes[0] / 64;
    int M = in_sizes[24];
    int BATCH = in_sizes[2];

    size_t N64 = (size_t)N * 64, M64 = (size_t)M * 64;
    float* out_y    = (float*)d_out;
    float* out_loss = out_y + N64;

    size_t wt_bytes  = (size_t)4 * 27 * 4096 * sizeof(bf16);   // 884736
    size_t wt5_bytes = (size_t)256 * 64 * sizeof(bf16);        // 32768
    size_t wtp_bytes = (size_t)8 * 4096 * sizeof(bf16);        // 65536
    size_t yf_bytes  = 4 * N64;
    size_t required = 64 + 4 * M64 + yf_bytes + wt_bytes + wt5_bytes + wtp_bytes;
    if (ws_size < required) {
        float code = 200.f + (float)(ws_size >> 20);
        k_code<<<512, 256, 0, stream>>>(out_y, N64, code);
        k_code<<<1, 64, 0, stream>>>(out_loss, 1, code);
        return;
    }

    char* wsb = (char*)d_ws;
    float* accum = (float*)wsb;
    bf16* buf1 = (bf16*)(wsb + 64);
    bf16* buf2 = buf1 + M64;
    float* yf  = (float*)(buf2 + M64);        // [N][64] f32 y staging
    bf16* WT   = (bf16*)((char*)yf + yf_bytes);
    bf16* WT1 = WT;
    bf16* WT2 = WT + (size_t)27 * 4096;
    bf16* WT3 = WT + (size_t)2 * 27 * 4096;
    bf16* WT4 = WT + (size_t)3 * 27 * 4096;
    bf16* WT5 = WT + (size_t)4 * 27 * 4096;   // [256][64]
    bf16* WTP = WT5 + (size_t)256 * 64;       // [8][64][64]

    hipMemsetAsync(wsb, 0, 64, stream);

    k_wt<<<108, 256, 0, stream>>>(Wb1, Wb2, Wp0c, Wp1c, WT);
    k_wt5<<<1, 256, 0, stream>>>(Wp1l, WT5);
    k_wtp<<<8, 256, 0, stream>>>(Wp0l, WTP);

    int blocksN32 = (N + 31) / 32;
    int blocksN64 = (N + 63) / 64;     // G=1: 64 rows/block
    int blocksM256 = (M + 255) / 256;  // G=4: 256 rows/block

    k_dec<<<blocksN32, 256, 0, stream>>>(rec_F, bins1_F, W_dec, b_dec, a_dec, buf1, N);

    k_sconv_mfma<1, false, false><<<blocksN64, 256, 0, stream>>>(
        buf1, nbr_rec, WT1, bb1, ab1, nullptr, buf2, nullptr, N);

    // stage 3: y bf16 in-place into buf1 (res==out, same-thread RW), f32 to yf
    k_sconv_mfma<1, true, true><<<blocksN64, 256, 0, stream>>>(
        buf2, nbr_rec, WT2, bb2, ab2, buf1, buf1, yf, N);

    k_sconv_mfma<1, false, false><<<blocksN64, 256, 0, stream>>>(
        buf1, nbr_rec, WT3, bp0c, ap0, nullptr, buf2, nullptr, N);

    k_p0l_mfma<<<1024, 256, 0, stream>>>(buf2, WTP, bp0l, child_pidx, child_bit, buf1, M);

    k_sconv_mfma<4, false, false><<<blocksM256, 256, 0, stream>>>(
        buf1, nbr_child, WT4, bp1c, ap1, nullptr, buf2, nullptr, M);

    k_loss_mfma<<<1024, 256, 0, stream>>>(buf2, WT5, bp1l, bins0, oct_kernel,
                                          ref_batch, pn, accum, M);
    k_finish<<<1, 64, 0, stream>>>(accum, out_loss, BATCH);

    // publish y LAST: nothing runs after this that could touch d_out
    hipMemcpyAsync(out_y, yf, yf_bytes, hipMemcpyDeviceToDevice, stream);
}